// Round 5
// baseline (3771.273 us; speedup 1.0000x reference)
//
#include <hip/hip_runtime.h>
#include <stdint.h>

typedef __attribute__((ext_vector_type(4))) int   i32x4;
typedef __attribute__((ext_vector_type(4))) float f32x4;
typedef __attribute__((ext_vector_type(8))) short bf16x8;
typedef unsigned short u16;
typedef unsigned char  u8;

#define QMAX 32512.0f
#define ZSCL 2047.0f
#define INV_ZSCL (1.0f/2047.0f)

__device__ __forceinline__ float bf2f(u16 u) {
    union { uint32_t i; float f; } v; v.i = ((uint32_t)u) << 16; return v.f;
}
__device__ __forceinline__ u16 f2bf(float f) {
    union { float f; uint32_t i; } v; v.f = f;
    uint32_t r = v.i + 0x7fffu + ((v.i >> 16) & 1u);
    return (u16)(r >> 16);
}
__device__ __forceinline__ float sigf(float x) { return 1.0f / (1.0f + __expf(-x)); }
__device__ __forceinline__ i32x4 mfma8(i32x4 a, i32x4 b, i32x4 c) {
    return __builtin_amdgcn_mfma_i32_16x16x64_i8(a, b, c, 0, 0, 0);
}
__device__ __forceinline__ f32x4 mfmabf(bf16x8 a, bf16x8 b, f32x4 c) {
    return __builtin_amdgcn_mfma_f32_16x16x32_bf16(a, b, c, 0, 0, 0);
}
__device__ __forceinline__ void qsplit(float v, float s, int& hi, int& lo) {
    float q = fminf(fmaxf(v * s, -QMAX), QMAX);
    int qi = (int)rintf(q);
    lo = ((qi + 128) & 255) - 128;
    hi = (qi - lo) >> 8;
}
// lgkm-only barrier: LDS producer/consumer sync WITHOUT draining vmcnt
// (U-stream loads + merged stores + zx prefetch stay in flight across it)
__device__ __forceinline__ void bar_lgk() {
    __builtin_amdgcn_sched_barrier(0);
    asm volatile("s_waitcnt lgkmcnt(0)" ::: "memory");
    __builtin_amdgcn_s_barrier();
    __builtin_amdgcn_sched_barrier(0);
}

// ---------------- per-column max |U|
__global__ __launch_bounds__(256) void uscale_kernel(
    const float* __restrict__ U0, const float* __restrict__ U1,
    const float* __restrict__ U2, const float* __restrict__ U3,
    float* __restrict__ Uscale)
{
    int idx = blockIdx.x * 256 + threadIdx.x;
    if (idx < 4096) {
        int l = idx >> 10, col = idx & 1023;
        const float* U = (l==0)?U0:(l==1)?U1:(l==2)?U2:U3;
        float m = 0.f;
        for (int k = 0; k < 256; ++k) m = fmaxf(m, fabsf(U[k*1024 + col]));
        Uscale[idx] = m;
    }
}

// ---------------- pack U to i8 hi/lo, UNIT layout for the register ring:
// Upk3[lstm][unit 16][w 8][half 2][m 2][lane 64][16B]; unit = kt*4+g;
// cb = g*16+2w+m; col = cb*16+(lane&15); k = kt*64+(lane>>4)*16+i
// per (unit,w,lane): {hi_m0 @0, hi_m1 @1024, lo_m0 @2048, lo_m1 @3072}
__global__ __launch_bounds__(256) void upack_kernel(
    const float* __restrict__ U0, const float* __restrict__ U1,
    const float* __restrict__ U2, const float* __restrict__ U3,
    const float* __restrict__ Uscale, u8* __restrict__ Upk3)
{
    int idx = blockIdx.x * 256 + threadIdx.x;      // one u32 per thread, < 524288
    int byte = idx * 4;
    int l = byte >> 19;   int off = byte & 0x7FFFF;
    int unit = off >> 15; int r1 = off & 0x7FFF;
    int w = r1 >> 12;     int r2 = r1 & 0xFFF;
    int half = r2 >> 11;  int m = (r2 >> 10) & 1;
    int lb = r2 & 1023;
    int lane = lb >> 4;   int ib = lb & 15;
    int g = unit & 3, kt = unit >> 2;
    const float* U = (l==0)?U0:(l==1)?U1:(l==2)?U2:U3;
    int cb = g*16 + 2*w + m;
    int col = cb*16 + (lane & 15);
    float s = QMAX / fmaxf(Uscale[l*1024 + col], 1e-30f);
    uint32_t wd = 0;
    for (int j = 0; j < 4; ++j) {
        int k = kt*64 + (lane >> 4)*16 + ib + j;
        int hi, lo; qsplit(U[k*1024 + col], s, hi, lo);
        int b = half ? lo : hi;
        wd |= ((uint32_t)(b & 255)) << (8*j);
    }
    ((uint32_t*)Upk3)[idx] = wd;
}

// ---------------- W -> bf16 pair (hi + residual), [lstm][col][96], zero-padded k>=F
__global__ __launch_bounds__(256) void wpair_kernel(
    const float* __restrict__ W0, const float* __restrict__ W1,
    const float* __restrict__ W2, const float* __restrict__ W3,
    u16* __restrict__ Wbh, u16* __restrict__ Wbl)
{
    int idx = blockIdx.x * 256 + threadIdx.x;      // < 393216
    int lstm = idx / 98304; int rem = idx - lstm*98304;
    int col = rem / 96; int k = rem - col*96;
    const int F = (lstm==0)?80:(lstm==1)?64:(lstm==2)?48:32;
    const float* W = (lstm==0)?W0:(lstm==1)?W1:(lstm==2)?W2:W3;
    float v = (k < F) ? W[k*1024 + col] : 0.f;
    u16 hb = f2bf(v);
    Wbh[idx] = hb;
    Wbl[idx] = f2bf(v - bf2f(hb));
}

// ---------------- z_x GEMM -> i16 (R4 verbatim)
__global__ __launch_bounds__(512) void zx_gemm_kernel(
    const float* __restrict__ x0, const float* __restrict__ x1,
    const float* __restrict__ x2, const float* __restrict__ x3,
    const float* __restrict__ bb0, const float* __restrict__ bb1,
    const float* __restrict__ bb2, const float* __restrict__ bb3,
    const u16* __restrict__ Wbh, const u16* __restrict__ Wbl,
    short* __restrict__ zxg, u8* __restrict__ maskb, int t0, int nt)
{
    const int lstm = blockIdx.x >> 7;
    const int b = blockIdx.x & 127;
    const int F = (lstm==0)?80:(lstm==1)?64:(lstm==2)?48:32;
    const int KT = (F + 31) >> 5;
    const float* xin  = (lstm==0)?x0:(lstm==1)?x1:(lstm==2)?x2:x3;
    const float* bias = (lstm==0)?bb0:(lstm==1)?bb1:(lstm==2)?bb2:bb3;

    const int tid = threadIdx.x;
    const int w = tid >> 6, l = tid & 63, lg = l >> 4, ln = l & 15;
    const int rr = tid >> 5, cc = tid & 31;

    __shared__ u16 xh[16][104], xl[16][104];
    __shared__ u8 anyf[16][32];

    float bv[8];
    size_t wo_base[8];
#pragma unroll
    for (int ti = 0; ti < 8; ++ti) {
        int g = ti >> 1, m = ti & 1;
        int col = (g*16 + 2*w + m)*16 + ln;
        bv[ti] = bias[col];
        wo_base[ti] = ((size_t)(lstm*1024) + col)*96 + lg*8;
    }

    const int TT = nt >> 4;
    for (int tt = 0; tt < TT; ++tt) {
        const int tb = t0 + tt*16;
        bool any = false;
#pragma unroll
        for (int j = 0; j < 3; ++j) {
            int f = cc + 32*j;
            float v = (f < F) ? xin[((size_t)b*256 + tb + rr)*F + f] : 0.f;
            if (f < F) any = any || (v != -1.0f);
            u16 hb = f2bf(v);
            xh[rr][f] = hb;
            xl[rr][f] = f2bf(v - bf2f(hb));
        }
        anyf[rr][cc] = any ? 1 : 0;
        __syncthreads();
        if (tid < 16) {
            int mm = 0;
#pragma unroll
            for (int q = 0; q < 32; ++q) mm |= anyf[tid][q];
            maskb[((size_t)(lstm*128 + b))*256 + tb + tid] = (u8)(mm ? 1 : 0);
        }

        f32x4 acc[8];
#pragma unroll
        for (int ti = 0; ti < 8; ++ti) acc[ti] = (f32x4){0.f,0.f,0.f,0.f};

        for (int kt = 0; kt < KT; ++kt) {
            bf16x8 ah = *(const bf16x8*)&xh[ln][kt*32 + lg*8];
            bf16x8 al = *(const bf16x8*)&xl[ln][kt*32 + lg*8];
#pragma unroll
            for (int ti = 0; ti < 8; ++ti) {
                const u16* wp = Wbh + wo_base[ti] + kt*32;
                const u16* wq = Wbl + wo_base[ti] + kt*32;
                bf16x8 wh = *(const bf16x8*)wp;
                bf16x8 wl = *(const bf16x8*)wq;
                acc[ti] = mfmabf(ah, wh, acc[ti]);
                acc[ti] = mfmabf(al, wh, acc[ti]);
                acc[ti] = mfmabf(ah, wl, acc[ti]);
            }
        }
#pragma unroll
        for (int reg = 0; reg < 4; ++reg) {
            int tl = tt*16 + lg*4 + reg;
            uint32_t d[4];
#pragma unroll
            for (int g = 0; g < 4; ++g) {
                int q0 = (int)rintf(fminf(fmaxf((acc[2*g  ][reg] + bv[2*g  ]) * ZSCL, -32767.f), 32767.f));
                int q1 = (int)rintf(fminf(fmaxf((acc[2*g+1][reg] + bv[2*g+1]) * ZSCL, -32767.f), 32767.f));
                d[g] = ((uint32_t)q0 & 0xffffu) | (((uint32_t)q1 & 0xffffu) << 16);
            }
            i32x4 out = { (int)d[0], (int)d[1], (int)d[2], (int)d[3] };
            short* dst = zxg + ((size_t)(lstm*128 + b)*nt + tl)*1024 + (w*16 + ln)*8;
            *(i32x4*)dst = out;
        }
        __syncthreads();
    }
}

// ---------------- recurrence: all-direct U streaming (L2 -> VGPR register ring)
// 32 WGs (same-lstm XCD pairs), 512 thr (8 waves). No LDS transit for U.
__global__ __launch_bounds__(512, 2) void lstm_rec_kernel(
    const u8* __restrict__ Upk3, const short* __restrict__ zxg,
    const u8* __restrict__ maskb, const float* __restrict__ Uscale,
    float* __restrict__ c_state, float* __restrict__ h_state,
    u16* __restrict__ merged, int t0, int nt)
{
    const int bx = blockIdx.x;
    const int lstm = (bx & 7) >> 1;                 // lstm l on XCDs 2l, 2l+1
    const int rb   = ((bx >> 3) << 1) | (bx & 1);
    const int b0 = rb * 16;

    const int tid = threadIdx.x;
    const int w = tid >> 6, l = tid & 63, lg = l >> 4, ln = l & 15;
    const u8* Ubl = Upk3 + (size_t)lstm * 524288 + (size_t)w * 4096 + (size_t)l * 16;

    __shared__ u8 qA[2][16][256];        // [half][row][swizzled] 8KB
    __shared__ u8 mask_l[16][256];       // 4KB
    __shared__ float wmax[16][8];

    for (int i = tid; i < 4096; i += 512) {
        int r = i >> 8, s = i & 255;
        mask_l[r][s] = (s < nt) ? maskb[((size_t)(lstm*128 + b0 + r))*256 + t0 + s] : (u8)1;
    }
    __syncthreads();

    const int u0 = 32*w + ln, u1 = u0 + 16;
    float cU[8];
#pragma unroll
    for (int ti = 0; ti < 8; ++ti) {
        int col = (ti >> 1)*256 + 32*w + 16*(ti & 1) + ln;
        cU[ti] = Uscale[lstm*1024 + col] * (1.0f/(QMAX*QMAX));
    }

    float c_[2][4], h_[2][4];
    if (t0 == 0) {
#pragma unroll
        for (int m = 0; m < 2; ++m)
#pragma unroll
            for (int rg = 0; rg < 4; ++rg) { c_[m][rg] = 0.f; h_[m][rg] = 0.f; }
    } else {
#pragma unroll
        for (int m = 0; m < 2; ++m)
#pragma unroll
            for (int rg = 0; rg < 4; ++rg) {
                size_t o = ((size_t)(lstm*128 + b0 + lg*4 + rg))*256 + (m==0?u0:u1);
                c_[m][rg] = c_state[o]; h_[m][rg] = h_state[o];
            }
    }

    const u8* qA0 = &qA[0][ln][0];
    const u8* qA1 = &qA[1][ln][0];
    const short* zx_thr = zxg + ((size_t)(lstm*128 + b0)) * nt * 1024 + (w*16 + ln)*8;
    u16* mg0 = merged + ((size_t)b0 * 256 + t0) * 1024 + (size_t)lstm * 256;

    // U register ring: 4 slots x {hi_m0, hi_m1, lo_m0, lo_m1}
    i32x4 uf[4][4];
#define LOADU(UNIT, SLOT)                                                       \
    {                                                                           \
        const u8* _p = Ubl + (size_t)(UNIT) * 32768;                            \
        uf[SLOT][0] = *(const i32x4*)(_p);                                      \
        uf[SLOT][1] = *(const i32x4*)(_p + 1024);                               \
        uf[SLOT][2] = *(const i32x4*)(_p + 2048);                               \
        uf[SLOT][3] = *(const i32x4*)(_p + 3072);                               \
    }

    i32x4 zA[4], zB[4];
#pragma unroll
    for (int rg = 0; rg < 4; ++rg)
        zA[rg] = *(const i32x4*)(zx_thr + (size_t)(lg*4 + rg) * nt * 1024);
    // prologue: fill ring with units 0..3
#pragma unroll
    for (int p = 0; p < 4; ++p) LOADU(p, p);

    auto STEP = [&](int s, i32x4 (&zc)[4], i32x4 (&zn)[4]) {
        // prefetch zx(s+1) into registers (clamped; constant load count)
        const int sn = (s + 1 < nt) ? (s + 1) : s;
#pragma unroll
        for (int rg = 0; rg < 4; ++rg)
            zn[rg] = *(const i32x4*)(zx_thr + ((size_t)(lg*4 + rg) * nt + sn) * 1024);

        // (1) per-row wave max of h (h >= 0)
#pragma unroll
        for (int rg = 0; rg < 4; ++rg) {
            float v = fmaxf(h_[0][rg], h_[1][rg]);
            v = fmaxf(v, __shfl_xor(v, 1));
            v = fmaxf(v, __shfl_xor(v, 2));
            v = fmaxf(v, __shfl_xor(v, 4));
            v = fmaxf(v, __shfl_xor(v, 8));
            if (ln == 0) wmax[lg*4 + rg][w] = v;
        }
        bar_lgk();   // B1

        // (2) global row max -> quantize h into qA (verified swizzle)
        float rmax_[4];
#pragma unroll
        for (int rg = 0; rg < 4; ++rg) {
            const int r = lg*4 + rg;
            float4 p0 = *(const float4*)&wmax[r][0];
            float4 p1 = *(const float4*)&wmax[r][4];
            float rm = fmaxf(fmaxf(fmaxf(p0.x,p0.y),fmaxf(p0.z,p0.w)),
                             fmaxf(fmaxf(p1.x,p1.y),fmaxf(p1.z,p1.w)));
            rmax_[rg] = rm;
            float qs = QMAX / fmaxf(rm, 1e-30f);
#pragma unroll
            for (int m = 0; m < 2; ++m) {
                const int u = (m == 0) ? u0 : u1;
                int hi, lo; qsplit(h_[m][rg], qs, hi, lo);
                int pos = (((u >> 4) ^ r) << 4) | (u & 15);
                qA[0][r][pos] = (u8)hi;
                qA[1][r][pos] = (u8)lo;
            }
        }
        bar_lgk();   // B2: qA visible

        // (3) h @ U: 16 units, register ring, 6 MFMA/unit
        i32x4 aP[8], aX[8];
#pragma unroll
        for (int ti = 0; ti < 8; ++ti) { aP[ti] = (i32x4){0,0,0,0}; aX[ti] = (i32x4){0,0,0,0}; }

        i32x4 hh, hl;
#pragma unroll
        for (int u2 = 0; u2 < 16; ++u2) {
            const int kt = u2 >> 2, g = u2 & 3, sl = u2 & 3;
            if (g == 0) {
                int slot = (kt*4 + lg) ^ ln;
                hh = *(const i32x4*)(qA0 + slot*16);
                hl = *(const i32x4*)(qA1 + slot*16);
            }
            aP[2*g  ] = mfma8(hh, uf[sl][0], aP[2*g  ]);
            aX[2*g  ] = mfma8(hl, uf[sl][0], aX[2*g  ]);
            aX[2*g  ] = mfma8(hh, uf[sl][2], aX[2*g  ]);
            aP[2*g+1] = mfma8(hh, uf[sl][1], aP[2*g+1]);
            aX[2*g+1] = mfma8(hl, uf[sl][1], aX[2*g+1]);
            aX[2*g+1] = mfma8(hh, uf[sl][3], aX[2*g+1]);
            LOADU((u2 + 4) & 15, sl);   // refill slot for next use (wraps across steps)
        }

        // (4) gates + state update + merged store
        u16* mgs = mg0 + (size_t)s * 1024;
#pragma unroll
        for (int rg = 0; rg < 4; ++rg) {
            const int r = lg*4 + rg;
            const int mk = mask_l[r][t0 ? s : s];   // s indexes chunk-local mask
            const i32x4 zv = zc[rg];
#pragma unroll
            for (int m = 0; m < 2; ++m) {
                const int u = (m == 0) ? u0 : u1;
                float zi = (float)(short)(m ? ((uint32_t)zv[0] >> 16) : ((uint32_t)zv[0] & 0xffffu)) * INV_ZSCL
                         + (65536.f*(float)aP[0+m][rg] + 256.f*(float)aX[0+m][rg]) * cU[0+m] * rmax_[rg];
                float zf = (float)(short)(m ? ((uint32_t)zv[1] >> 16) : ((uint32_t)zv[1] & 0xffffu)) * INV_ZSCL
                         + (65536.f*(float)aP[2+m][rg] + 256.f*(float)aX[2+m][rg]) * cU[2+m] * rmax_[rg];
                float zg = (float)(short)(m ? ((uint32_t)zv[2] >> 16) : ((uint32_t)zv[2] & 0xffffu)) * INV_ZSCL
                         + (65536.f*(float)aP[4+m][rg] + 256.f*(float)aX[4+m][rg]) * cU[4+m] * rmax_[rg];
                float zo = (float)(short)(m ? ((uint32_t)zv[3] >> 16) : ((uint32_t)zv[3] & 0xffffu)) * INV_ZSCL
                         + (65536.f*(float)aP[6+m][rg] + 256.f*(float)aX[6+m][rg]) * cU[6+m] * rmax_[rg];
                float ig = sigf(zi), fg = sigf(zf), og = sigf(zo);
                float gg = fmaxf(zg, 0.f);
                float cn = fg * c_[m][rg] + ig * gg;
                float hn = og * fmaxf(cn, 0.f);
                if (!mk) { cn = c_[m][rg]; hn = h_[m][rg]; }
                c_[m][rg] = cn; h_[m][rg] = hn;
                mgs[(size_t)r * 256 * 1024 + u] = f2bf(hn);
            }
        }
    };

    for (int s2 = 0; s2 < nt; s2 += 2) {
        STEP(s2,     zA, zB);
        STEP(s2 + 1, zB, zA);
    }
#undef LOADU

    if (t0 + nt < 256) {
#pragma unroll
        for (int m = 0; m < 2; ++m)
#pragma unroll
            for (int rg = 0; rg < 4; ++rg) {
                size_t o = ((size_t)(lstm*128 + b0 + lg*4 + rg))*256 + (m==0?u0:u1);
                c_state[o] = c_[m][rg]; h_state[o] = h_[m][rg];
            }
    }
}

// ---------------- attention + output head (verbatim)
__global__ __launch_bounds__(256) void attn_kernel(
    const u16* __restrict__ merged,
    const float* __restrict__ w_att, const float* __restrict__ b_att,
    const float* __restrict__ w_out, const float* __restrict__ b_out,
    float* __restrict__ out)
{
    const int b = blockIdx.x;
    const int tid = threadIdx.x;
    const int wv = tid >> 6;
    const int l = tid & 63;

    __shared__ float watt_s[1024];
    __shared__ float wout_s[1024];
    __shared__ float sc[256];
    __shared__ float red[8];

    for (int i = tid; i < 1024; i += 256) {
        watt_s[i] = w_att[i];
        wout_s[i] = w_out[i];
    }
    __syncthreads();

    const float batt = b_att[0];

    for (int tt = wv; tt < 256; tt += 4) {
        const u16* row = merged + ((size_t)b * 256 + tt) * 1024 + l * 16;
        uint4 q0 = *(const uint4*)(row);
        uint4 q1 = *(const uint4*)(row + 8);
        const float* wp = &watt_s[l * 16];
        uint32_t qa[8] = {q0.x, q0.y, q0.z, q0.w, q1.x, q1.y, q1.z, q1.w};
        float s = 0.f;
#pragma unroll
        for (int i = 0; i < 8; ++i) {
            s += bf2f((u16)(qa[i] & 0xffffu)) * wp[2 * i];
            s += bf2f((u16)(qa[i] >> 16)) * wp[2 * i + 1];
        }
#pragma unroll
        for (int o = 32; o > 0; o >>= 1) s += __shfl_xor(s, o);
        if (l == 0) sc[tt] = tanhf(s + batt);
    }
    __syncthreads();

    float v = sc[tid];
    float mx = v;
#pragma unroll
    for (int o = 32; o > 0; o >>= 1) mx = fmaxf(mx, __shfl_xor(mx, o));
    if (l == 0) red[wv] = mx;
    __syncthreads();
    mx = fmaxf(fmaxf(red[0], red[1]), fmaxf(red[2], red[3]));
    float p = __expf(v - mx);
    float sm = p;
#pragma unroll
    for (int o = 32; o > 0; o >>= 1) sm += __shfl_xor(sm, o);
    if (l == 0) red[4 + wv] = sm;
    __syncthreads();
    sm = red[4] + red[5] + red[6] + red[7];
    p /= sm;
    sc[tid] = p;
    __syncthreads();

    const int d0 = tid * 4;
    float a0 = 0.f, a1 = 0.f, a2 = 0.f, a3 = 0.f;
    for (int t = 0; t < 256; ++t) {
        float pp = sc[t];
        const u16* mp = merged + ((size_t)b * 256 + t) * 1024 + d0;
        ushort4 q = *(const ushort4*)mp;
        a0 += pp * bf2f(q.x);
        a1 += pp * bf2f(q.y);
        a2 += pp * bf2f(q.z);
        a3 += pp * bf2f(q.w);
    }
    float part = a0 * wout_s[d0] + a1 * wout_s[d0 + 1] + a2 * wout_s[d0 + 2] + a3 * wout_s[d0 + 3];
#pragma unroll
    for (int o = 32; o > 0; o >>= 1) part += __shfl_xor(part, o);
    __syncthreads();
    if (l == 0) red[wv] = part;
    __syncthreads();
    if (tid == 0) {
        float tot = red[0] + red[1] + red[2] + red[3] + b_out[0];
        out[b] = 1.0f / (1.0f + __expf(-tot));
    }
}

extern "C" void kernel_launch(void* const* d_in, const int* in_sizes, int n_in,
                              void* d_out, int out_size, void* d_ws, size_t ws_size,
                              hipStream_t stream) {
    (void)in_sizes; (void)n_in; (void)out_size;
    const float* x[4]; const float* W[4]; const float* U[4]; const float* bb[4];
    for (int i = 0; i < 4; ++i) {
        x[i]  = (const float*)d_in[4 * i + 0];
        W[i]  = (const float*)d_in[4 * i + 1];
        U[i]  = (const float*)d_in[4 * i + 2];
        bb[i] = (const float*)d_in[4 * i + 3];
    }
    const float* w_att = (const float*)d_in[16];
    const float* b_att = (const float*)d_in[17];
    const float* w_out = (const float*)d_in[18];
    const float* b_out = (const float*)d_in[19];

    u8* base = (u8*)d_ws;
    size_t off = 0;
    auto alloc = [&](size_t n) { u8* p = base + off; off += (n + 255) & ~(size_t)255; return p; };
    u16*   merged  = (u16*)  alloc(67108864);        // [128][256][1024] bf16
    u8*    Upk3    =         alloc(2097152);         // i8 hi/lo, unit layout
    u16*   Wbh     = (u16*)  alloc(786432);          // bf16 pair
    u16*   Wbl     = (u16*)  alloc(786432);
    float* Uscale  = (float*)alloc(16384);
    u8*    maskb   =         alloc(131072);
    float* c_state = (float*)alloc(524288);
    float* h_state = (float*)alloc(524288);
    size_t fixed = off;

    int nt = 256;                                     // zx chunk = nt MB; adapt to ws_size
    while (nt > 16 && fixed + (size_t)nt * 1048576 > ws_size) nt >>= 1;
    short* zxg = (short*)alloc((size_t)nt * 1048576);

    uscale_kernel<<<dim3(16),   dim3(256), 0, stream>>>(U[0], U[1], U[2], U[3], Uscale);
    upack_kernel <<<dim3(2048), dim3(256), 0, stream>>>(U[0], U[1], U[2], U[3], Uscale, Upk3);
    wpair_kernel <<<dim3(1536), dim3(256), 0, stream>>>(W[0], W[1], W[2], W[3], Wbh, Wbl);

    for (int t0 = 0; t0 < 256; t0 += nt) {
        zx_gemm_kernel<<<dim3(512), dim3(512), 0, stream>>>(
            x[0], x[1], x[2], x[3], bb[0], bb[1], bb[2], bb[3],
            Wbh, Wbl, zxg, maskb, t0, nt);
        lstm_rec_kernel<<<dim3(32), dim3(512), 0, stream>>>(
            Upk3, zxg, maskb, Uscale, c_state, h_state, merged, t0, nt);
    }

    attn_kernel<<<dim3(128), dim3(256), 0, stream>>>(
        merged, w_att, b_att, w_out, b_out, (float*)d_out);
}